// Round 6
// baseline (123.057 us; speedup 1.0000x reference)
//
#include <hip/hip_runtime.h>
#include <math.h>

#define N 1024
#define C 81
#define F 1024
#define K 100
#define NC1 80              // foreground classes
#define MAXC (NC1 * N)
#define HBASE 0x3D00        // hist bucket base (float bits >> 16)
#define HSIZE 1024          // covers score in (0.05, 1]
#define SELCAP 2048

#define SCORE_THRESH 0.05f
#define NMS_THRESH   0.5f
#define BBOX_CLIP    4.135166556742356f   // log(1000/16)
#define IMG_W1       1215.0f
#define IMG_H1       799.0f

#define MAGIC_INIT 0x13572468
#define MAGIC_SEL  0x2468ACE0

typedef unsigned long long u64;
typedef unsigned int u32;

#define SCOPE __HIP_MEMORY_SCOPE_AGENT
#define LOADA(p)    __hip_atomic_load((p), __ATOMIC_RELAXED, SCOPE)
#define STOREA(p,v) __hip_atomic_store((p), (v), __ATOMIC_RELAXED, SCOPE)

struct Sync {
    int flag_init; int p0[31];
    int done2;     int p1[31];
    int flag3;     int p2[31];
    int counter;   int p3[31];
};

__device__ __forceinline__ float4 decode_box(float4 rb, float4 pb) {
    float w  = pb.z - pb.x + 1.0f, h = pb.w - pb.y + 1.0f;
    float cx = pb.x + 0.5f * w,   cy = pb.y + 0.5f * h;
    float dx = rb.x / 10.0f, dy = rb.y / 10.0f;
    float dw = fminf(rb.z / 5.0f, BBOX_CLIP);
    float dh = fminf(rb.w / 5.0f, BBOX_CLIP);
    float pcx = dx * w + cx, pcy = dy * h + cy;
    float pw = expf(dw) * w, ph = expf(dh) * h;
    float x1 = pcx - 0.5f * pw,        y1 = pcy - 0.5f * ph;
    float x2 = pcx + 0.5f * pw - 1.0f, y2 = pcy + 0.5f * ph - 1.0f;
    x1 = fminf(fmaxf(x1, 0.0f), IMG_W1);
    y1 = fminf(fmaxf(y1, 0.0f), IMG_H1);
    x2 = fminf(fmaxf(x2, 0.0f), IMG_W1);
    y2 = fminf(fmaxf(y2, 0.0f), IMG_H1);
    return make_float4(x1, y1, x2, y2);
}

// One kernel, 100 blocks x 256 threads. Blocks 0..79: per-class softmax
// (recomputed from logits -- no bulk intermediate arrays) + compact + sort +
// sequential NMS + publish candidates via write-through agent atomics.
// Block 0 then radix-selects top-K; all 100 blocks gather one detection.
// L2 stays clean across syncs -> release/acquire fences are cheap.
__global__ __launch_bounds__(256) void k_fused(
    const float* __restrict__ logits, const float* __restrict__ boxreg,
    const float* __restrict__ pboxes, const float* __restrict__ feats,
    u64* ckey, u32* cmeta, u64* cbox2, int* hist,
    u64* sel_key, u32* sel_slot, Sync* sync, float* __restrict__ out)
{
    const int b = blockIdx.x, tid = threadIdx.x;

    __shared__ u64    skey64[N];      // 8 KB
    __shared__ int    scnt[256];      // 1 KB
    __shared__ float4 sbox[N];        // 16 KB (V>64 fallback)
    __shared__ float  sarea[N];       // 4 KB
    __shared__ int    skeep[N];       // 4 KB
    __shared__ u64    selk[SELCAP];   // 16 KB (select)
    __shared__ u32    sels[SELCAP];   // 8 KB
    __shared__ int    sb_bstar, scount;
    __shared__ u64    wk[4];
    __shared__ int    wp[4];

    // ---- init (block 0): zero sync + hist at coherence point ----
    if (b == 0) {
        for (int i = tid; i < HSIZE; i += 256) STOREA(&hist[i], 0);
        if (tid == 0) {
            STOREA(&sync->done2, 0);
            STOREA(&sync->flag3, 0);
            STOREA(&sync->counter, 0);
        }
        __syncthreads();
        if (tid == 0)
            __hip_atomic_store(&sync->flag_init, MAGIC_INIT, __ATOMIC_RELEASE, SCOPE);
    }

    // ---- per-class work: blocks 0..79 ----
    if (b < NC1) {
        const int c = b;

        // per-class softmax: thread owns proposals 4t..4t+3
        float sc4[4];
        #pragma unroll
        for (int i = 0; i < 4; ++i) {
            int n = tid * 4 + i;
            const float4* lp = (const float4*)(logits + (size_t)n * C);
            float last = logits[(size_t)n * C + 80];
            float mx = last;
            float4 v;
            #pragma unroll
            for (int q = 0; q < 20; ++q) {
                v = lp[q];
                mx = fmaxf(mx, fmaxf(fmaxf(v.x, v.y), fmaxf(v.z, v.w)));
            }
            float sum = expf(last - mx);
            #pragma unroll
            for (int q = 0; q < 20; ++q) {
                v = lp[q];
                sum += expf(v.x - mx) + expf(v.y - mx) + expf(v.z - mx) + expf(v.w - mx);
            }
            sc4[i] = expf(logits[(size_t)n * C + (c + 1)] - mx) / sum;
        }

        // order-preserving compaction of valid proposals
        int f0 = sc4[0] > SCORE_THRESH, f1 = sc4[1] > SCORE_THRESH;
        int f2 = sc4[2] > SCORE_THRESH, f3 = sc4[3] > SCORE_THRESH;
        int mycount = f0 + f1 + f2 + f3;
        scnt[tid] = mycount;
        __syncthreads();
        for (int off = 1; off < 256; off <<= 1) {
            int v = scnt[tid];
            int a = (tid >= off) ? scnt[tid - off] : 0;
            __syncthreads();
            scnt[tid] = v + a;
            __syncthreads();
        }
        int base = scnt[tid] - mycount;
        int V = scnt[255];
        {
            int p0 = tid * 4, pos = base;
            if (f0) skey64[pos++] = ((u64)__float_as_uint(sc4[0]) << 32) | (u32)~(u32)(p0);
            if (f1) skey64[pos++] = ((u64)__float_as_uint(sc4[1]) << 32) | (u32)~(u32)(p0 + 1);
            if (f2) skey64[pos++] = ((u64)__float_as_uint(sc4[2]) << 32) | (u32)~(u32)(p0 + 2);
            if (f3) skey64[pos++] = ((u64)__float_as_uint(sc4[3]) << 32) | (u32)~(u32)(p0 + 3);
        }
        __syncthreads();

        u64    mykey = 0ull;
        int    mykept = 0, myidx = 0;
        float4 mybox = make_float4(0.f, 0.f, 0.f, 0.f);

        if (V > 0 && V <= 64) {
            if (tid < 64) {
                int lane = tid;
                u64 key = (lane < V) ? skey64[lane] : 0ull;
                // descending bitonic over 64 lanes (keys unique; 0-pad sinks)
                for (int k = 2; k <= 64; k <<= 1) {
                    for (int j = k >> 1; j > 0; j >>= 1) {
                        u64 other = __shfl_xor(key, j);
                        bool takeMax = (((lane & j) == 0) == ((lane & k) == 0));
                        bool gt = key > other;
                        key = (takeMax == gt) ? key : other;
                    }
                }
                bool act = key != 0ull;
                float area = 0.0f;
                if (act) {
                    myidx = (int)(~(u32)(key & 0xffffffffu));
                    float4 rb = ((const float4*)boxreg)[(size_t)myidx * C + (c + 1)];
                    float4 pb = ((const float4*)pboxes)[myidx];
                    mybox = decode_box(rb, pb);
                    area = (mybox.z - mybox.x + 1.0f) * (mybox.w - mybox.y + 1.0f);
                }
                int kept = act ? 1 : 0;
                for (int i = 0; i + 1 < V; ++i) {
                    int   ki  = __shfl(kept, i);
                    float bix = __shfl(mybox.x, i), biy = __shfl(mybox.y, i);
                    float biz = __shfl(mybox.z, i), biw = __shfl(mybox.w, i);
                    float ai  = __shfl(area, i);
                    if (ki && lane > i && kept) {
                        float lx = fmaxf(bix, mybox.x), ly = fmaxf(biy, mybox.y);
                        float rx = fminf(biz, mybox.z), ry = fminf(biw, mybox.w);
                        float ww = fmaxf(rx - lx + 1.0f, 0.0f);
                        float hh = fmaxf(ry - ly + 1.0f, 0.0f);
                        float inter = ww * hh;
                        float iou = inter / (ai + area - inter);
                        if (iou > NMS_THRESH) kept = 0;
                    }
                }
                mykey = key; mykept = kept;
            }
        } else if (V > 64) {
            int P = 128;
            while (P < V) P <<= 1;
            for (int i = V + tid; i < P; i += 256) skey64[i] = 0ull;
            __syncthreads();
            for (int k = 2; k <= P; k <<= 1) {
                for (int j = k >> 1; j > 0; j >>= 1) {
                    for (int i = tid; i < P; i += 256) {
                        int ixj = i ^ j;
                        if (ixj > i) {
                            u64 a = skey64[i], bb2 = skey64[ixj];
                            bool desc = ((i & k) == 0);
                            if (desc ? (a < bb2) : (a > bb2)) { skey64[i] = bb2; skey64[ixj] = a; }
                        }
                    }
                    __syncthreads();
                }
            }
            for (int p = tid; p < V; p += 256) {
                int idx = (int)(~(u32)(skey64[p] & 0xffffffffu));
                float4 rb = ((const float4*)boxreg)[(size_t)idx * C + (c + 1)];
                float4 pb = ((const float4*)pboxes)[idx];
                float4 bb2 = decode_box(rb, pb);
                sbox[p]  = bb2;
                sarea[p] = (bb2.z - bb2.x + 1.0f) * (bb2.w - bb2.y + 1.0f);
                skeep[p] = 1;
            }
            __syncthreads();
            for (int i = 0; i < V; ++i) {
                if (skeep[i]) {
                    float4 bi = sbox[i];
                    float  ai = sarea[i];
                    for (int j = i + 1 + tid; j < V; j += 256) {
                        if (skeep[j]) {
                            float4 bj = sbox[j];
                            float lx = fmaxf(bi.x, bj.x), ly = fmaxf(bi.y, bj.y);
                            float rx = fminf(bi.z, bj.z), ry = fminf(bi.w, bj.w);
                            float ww = fmaxf(rx - lx + 1.0f, 0.0f);
                            float hh = fmaxf(ry - ly + 1.0f, 0.0f);
                            float inter = ww * hh;
                            float iou = inter / (ai + sarea[j] - inter);
                            if (iou > NMS_THRESH) skeep[j] = 0;
                        }
                    }
                }
                __syncthreads();
            }
        }

        // gate on init, then publish candidates via write-through atomics
        if (tid == 0) {
            while (LOADA(&sync->flag_init) != MAGIC_INIT) __builtin_amdgcn_s_sleep(2);
        }
        __syncthreads();

        if (V > 0 && V <= 64) {
            if (tid < 64 && mykept) {
                int pos = __hip_atomic_fetch_add(&sync->counter, 1, __ATOMIC_RELAXED, SCOPE);
                u32 sb = (u32)(mykey >> 32);
                STOREA(&ckey[pos], ((u64)sb << 32) | (u64)(u32)~(u32)(c * N + tid));
                STOREA(&cmeta[pos], ((u32)c << 10) | (u32)myidx);
                STOREA(&cbox2[(size_t)pos * 2],
                       ((u64)__float_as_uint(mybox.y) << 32) | __float_as_uint(mybox.x));
                STOREA(&cbox2[(size_t)pos * 2 + 1],
                       ((u64)__float_as_uint(mybox.w) << 32) | __float_as_uint(mybox.z));
                __hip_atomic_fetch_add(&hist[(int)(sb >> 16) - HBASE], 1, __ATOMIC_RELAXED, SCOPE);
            }
        } else if (V > 64) {
            for (int p = tid; p < V; p += 256) {
                if (skeep[p]) {
                    int pos = __hip_atomic_fetch_add(&sync->counter, 1, __ATOMIC_RELAXED, SCOPE);
                    u32 sb = (u32)(skey64[p] >> 32);
                    int idx = (int)(~(u32)(skey64[p] & 0xffffffffu));
                    float4 bb2 = sbox[p];
                    STOREA(&ckey[pos], ((u64)sb << 32) | (u64)(u32)~(u32)(c * N + p));
                    STOREA(&cmeta[pos], ((u32)c << 10) | (u32)idx);
                    STOREA(&cbox2[(size_t)pos * 2],
                           ((u64)__float_as_uint(bb2.y) << 32) | __float_as_uint(bb2.x));
                    STOREA(&cbox2[(size_t)pos * 2 + 1],
                           ((u64)__float_as_uint(bb2.w) << 32) | __float_as_uint(bb2.z));
                    __hip_atomic_fetch_add(&hist[(int)(sb >> 16) - HBASE], 1, __ATOMIC_RELAXED, SCOPE);
                }
            }
        }
        __syncthreads();
        if (tid == 0)
            __hip_atomic_fetch_add(&sync->done2, 1, __ATOMIC_RELEASE, SCOPE);
    }

    // ---- select: block 0, radix-select + bitonic top-K ----
    if (b == 0) {
        if (tid == 0) {
            while (LOADA(&sync->done2) != NC1) __builtin_amdgcn_s_sleep(2);
        }
        __syncthreads();
        __builtin_amdgcn_fence(__ATOMIC_ACQUIRE, "agent");

        int Msel = LOADA(&sync->counter);
        if (tid == 0) { sb_bstar = 0; scount = 0; }

        int lo = tid * 4;
        int h0 = LOADA(&hist[lo]),     h1 = LOADA(&hist[lo + 1]);
        int h2 = LOADA(&hist[lo + 2]), h3 = LOADA(&hist[lo + 3]);
        int lsum = h0 + h1 + h2 + h3;
        scnt[tid] = lsum;
        __syncthreads();
        for (int off = 1; off < 256; off <<= 1) {      // suffix scan
            int v = scnt[tid];
            int a = (tid + off < 256) ? scnt[tid + off] : 0;
            __syncthreads();
            scnt[tid] = v + a;
            __syncthreads();
        }
        int basek = scnt[tid] - lsum;
        if (basek < K && basek + lsum >= K) {
            int hh[4] = {h0, h1, h2, h3};
            int run = basek;
            for (int q = 3; q >= 0; --q) {
                if (run < K && run + hh[q] >= K) { sb_bstar = lo + q; break; }
                run += hh[q];
            }
        }
        __syncthreads();
        int bstar = sb_bstar;

        for (int p = tid; p < Msel; p += 256) {
            u64 kk = LOADA(&ckey[p]);
            int bb2 = (int)((kk >> 48) & 0xFFFF) - HBASE;
            if (bb2 >= bstar) {
                int pos = atomicAdd(&scount, 1);
                if (pos < SELCAP) { selk[pos] = kk; sels[pos] = (u32)p; }
            }
        }
        __syncthreads();
        int cnt = scount;

        if (cnt <= SELCAP) {
            int P = 128;
            while (P < cnt) P <<= 1;
            for (int i = cnt + tid; i < P; i += 256) selk[i] = 0ull;
            __syncthreads();
            for (int k = 2; k <= P; k <<= 1) {
                for (int j = k >> 1; j > 0; j >>= 1) {
                    for (int i = tid; i < P; i += 256) {
                        int ixj = i ^ j;
                        if (ixj > i) {
                            u64 a = selk[i], bb2 = selk[ixj];
                            bool desc = ((i & k) == 0);
                            if (desc ? (a < bb2) : (a > bb2)) {
                                selk[i] = bb2; selk[ixj] = a;
                                u32 tmp = sels[i]; sels[i] = sels[ixj]; sels[ixj] = tmp;
                            }
                        }
                    }
                    __syncthreads();
                }
            }
            if (tid < K) {
                STOREA(&sel_key[tid], selk[tid]);
                STOREA(&sel_slot[tid], sels[tid]);
            }
        } else {
            // exact fallback (tie flood): K rounds of argmax over global keys
            for (int k = 0; k < K; ++k) {
                u64 key = 0ull; int pos = -1;
                for (int p = tid; p < Msel; p += 256) {
                    u64 kk = LOADA(&ckey[p]);
                    if (kk > key) { key = kk; pos = p; }
                }
                for (int off = 32; off; off >>= 1) {
                    u64 ok2 = __shfl_down(key, off);
                    int op = __shfl_down(pos, off);
                    if (ok2 > key) { key = ok2; pos = op; }
                }
                if ((tid & 63) == 0) { wk[tid >> 6] = key; wp[tid >> 6] = pos; }
                __syncthreads();
                if (tid == 0) {
                    for (int w = 1; w < 4; ++w)
                        if (wk[w] > key) { key = wk[w]; pos = wp[w]; }
                    STOREA(&sel_key[k], key);
                    STOREA(&sel_slot[k], (u32)(pos < 0 ? 0 : pos));
                    if (key != 0ull) STOREA(&ckey[pos], 0ull);
                }
                __syncthreads();
            }
        }
        __syncthreads();
        if (tid == 0)
            __hip_atomic_store(&sync->flag3, MAGIC_SEL, __ATOMIC_RELEASE, SCOPE);
    }

    // ---- gather: all 100 blocks, one detection each ----
    if (tid == 0) {
        while (LOADA(&sync->flag3) != MAGIC_SEL) __builtin_amdgcn_s_sleep(2);
    }
    __syncthreads();
    __builtin_amdgcn_fence(__ATOMIC_ACQUIRE, "agent");
    {
        u64 key  = LOADA(&sel_key[b]);
        u32 slot = LOADA(&sel_slot[b]);
        bool okk = key != 0ull;
        float s = okk ? __uint_as_float((u32)(key >> 32)) : 0.0f;
        float4 bb = make_float4(0.f, 0.f, 0.f, 0.f);
        int label = 0, orig = 0;
        if (okk) {
            u32 meta = LOADA(&cmeta[slot]);
            orig  = (int)(meta & 1023u);
            label = (int)(meta >> 10) + 1;
            u64 lo2 = LOADA(&cbox2[(size_t)slot * 2]);
            u64 hi2 = LOADA(&cbox2[(size_t)slot * 2 + 1]);
            bb.x = __uint_as_float((u32)lo2); bb.y = __uint_as_float((u32)(lo2 >> 32));
            bb.z = __uint_as_float((u32)hi2); bb.w = __uint_as_float((u32)(hi2 >> 32));
        }
        if (tid == 0) {
            out[b * 4 + 0] = bb.x; out[b * 4 + 1] = bb.y;
            out[b * 4 + 2] = bb.z; out[b * 4 + 3] = bb.w;
            out[K * 4 + b] = s;
            out[K * 4 + K + K * F + b] = (float)label;
        }
        const float4* src = (const float4*)(feats + (size_t)orig * F);
        float4* dst = (float4*)(out + K * 4 + K + (size_t)b * F);
        float4 z = make_float4(0.f, 0.f, 0.f, 0.f);
        dst[tid] = okk ? src[tid] : z;       // 256 threads x float4 == F
    }
}

// ---------------------------------------------------------------------------
extern "C" void kernel_launch(void* const* d_in, const int* in_sizes, int n_in,
                              void* d_out, int out_size, void* d_ws, size_t ws_size,
                              hipStream_t stream)
{
    const float* logits = (const float*)d_in[0];   // [N,C]
    const float* boxreg = (const float*)d_in[1];   // [N,C*4]
    const float* pboxes = (const float*)d_in[2];   // [N,4]
    const float* feats  = (const float*)d_in[3];   // [N,F]
    float* out = (float*)d_out;

    char* ws = (char*)d_ws;
    size_t off = 0;
    auto alloc = [&](size_t bytes) {
        size_t cur = off;
        off = (off + bytes + 255) & ~(size_t)255;
        return cur;
    };
    u64*  ckey     = (u64*) (ws + alloc(sizeof(u64) * MAXC));
    u32*  cmeta    = (u32*) (ws + alloc(sizeof(u32) * MAXC));
    u64*  cbox2    = (u64*) (ws + alloc(sizeof(u64) * 2 * MAXC));
    int*  hist     = (int*) (ws + alloc(sizeof(int) * HSIZE));
    u64*  sel_key  = (u64*) (ws + alloc(sizeof(u64) * K));
    u32*  sel_slot = (u32*) (ws + alloc(sizeof(u32) * K));
    Sync* sync     = (Sync*)(ws + alloc(sizeof(Sync)));

    hipLaunchKernelGGL(k_fused, dim3(100), dim3(256), 0, stream,
                       logits, boxreg, pboxes, feats,
                       ckey, cmeta, cbox2, hist, sel_key, sel_slot, sync, out);
}